// Round 5
// baseline (785.394 us; speedup 1.0000x reference)
//
#include <hip/hip_runtime.h>
#include <stdint.h>

#define BATCH 64
#define H 512
#define W 512
#define NR 256

// Exact floor(sqrt(m)) for 0 <= m <= 65535. (float)m is exact (< 2^24) and
// sqrtf is correctly rounded; nearest integer gap of sqrt(non-square m) is
// >= ~1/(2*256) >> fp32 ulp at 256, so truncation is already exact. The two
// branchless fixups are pure insurance.
__device__ __forceinline__ int floor_isqrt(int m) {
    int f = (int)sqrtf((float)m);
    f -= (f * f > m);
    f += ((f + 1) * (f + 1) <= m);
    return f;
}

// One wave per (batch, ring). Ring membership: bin(dx,dy) == r
//   <=>  r^2 <= dx^2+dy^2 <= (r+1)^2 - 1
//   <=>  dx in [ceil_sqrt(r^2-dy^2), floor_sqrt((r+1)^2-1-dy^2)]  (plus mirror)
// Note all pixels with bin <= 255 have |dx|,|dy| <= 255, so no image-edge
// clipping is ever needed. Lanes split the mirrored row pairs; accumulators
// live in registers; butterfly shuffle-reduce at the end. No atomics, no LDS.
__global__ __launch_bounds__(256) void frc_rings(
    const float* __restrict__ f1r, const float* __restrict__ f1i,
    const float* __restrict__ f2r, const float* __restrict__ f2i,
    float* __restrict__ out)
{
    const int b    = blockIdx.y;
    const int rg   = blockIdx.x;            // 0..63
    const int w    = threadIdx.x >> 6;      // 0..3
    const int lane = threadIdx.x & 63;
    const int r    = w * 64 + rg;           // rings {rg, rg+64, rg+128, rg+192}
                                            // per block -> balanced work

    // address of center pixel (y=256, x=256) of image b
    const long long ctr = (long long)b * (H * W) + 256LL * W + 256LL;

    float acr = 0.f, aci = 0.f, ap1 = 0.f, ap2 = 0.f;

    const int r2  = r * r;
    const int m2c = (r + 1) * (r + 1) - 1;

    for (int i = lane; i <= r; i += 64) {   // i = |dy|
        const int dy2 = i * i;
        const int m2  = m2c - dy2;          // >= 2r >= 0 always
        const int m1  = r2 - dy2;
        const int hi  = floor_isqrt(m2);
        int lo;
        if (m1 <= 0) {
            lo = 0;
        } else {
            const int f = floor_isqrt(m1);
            lo = (f * f == m1) ? f : f + 1; // ceil_sqrt
        }

        const long long rowoff = (long long)i * W;

        #pragma unroll
        for (int s = 0; s < 2; ++s) {       // dy = +i and dy = -i
            if (s == 1 && i == 0) break;
            const long long rb = ctr + (s == 0 ? rowoff : -rowoff);

            int dx = lo;
            if (lo == 0) {                  // center column pixel, no mirror
                const float a1 = f1r[rb], b1 = f1i[rb];
                const float a2 = f2r[rb], b2 = f2i[rb];
                acr += a1 * a2 + b1 * b2;
                aci += b1 * a2 - a1 * b2;
                ap1 += a1 * a1 + b1 * b1;
                ap2 += a2 * a2 + b2 * b2;
                dx = 1;
            }
            for (; dx <= hi; ++dx) {
                const long long ip = rb + dx;
                const long long im = rb - dx;
                const float a1p = f1r[ip], b1p = f1i[ip];
                const float a2p = f2r[ip], b2p = f2i[ip];
                const float a1m = f1r[im], b1m = f1i[im];
                const float a2m = f2r[im], b2m = f2i[im];
                acr += a1p * a2p + b1p * b2p + a1m * a2m + b1m * b2m;
                aci += b1p * a2p - a1p * b2p + b1m * a2m - a1m * b2m;
                ap1 += a1p * a1p + b1p * b1p + a1m * a1m + b1m * b1m;
                ap2 += a2p * a2p + b2p * b2p + a2m * a2m + b2m * b2m;
            }
        }
    }

    // 64-lane butterfly reduction
    #pragma unroll
    for (int s = 32; s > 0; s >>= 1) {
        acr += __shfl_xor(acr, s, 64);
        aci += __shfl_xor(aci, s, 64);
        ap1 += __shfl_xor(ap1, s, 64);
        ap2 += __shfl_xor(ap2, s, 64);
    }

    if (lane == 0) {
        const float num = sqrtf(acr * acr + aci * aci);
        const float den = sqrtf(ap1 * ap2);
        out[(size_t)b * NR + r] = (den == 0.f) ? 0.f : num / den;
    }
}

extern "C" void kernel_launch(void* const* d_in, const int* in_sizes, int n_in,
                              void* d_out, int out_size, void* d_ws, size_t ws_size,
                              hipStream_t stream) {
    const float* f1r = (const float*)d_in[0];
    const float* f1i = (const float*)d_in[1];
    const float* f2r = (const float*)d_in[2];
    const float* f2i = (const float*)d_in[3];
    float* out = (float*)d_out;

    (void)in_sizes; (void)n_in; (void)out_size; (void)d_ws; (void)ws_size;

    dim3 grid(64, BATCH);   // 64 ring-groups x 64 batches, 4 waves/block
    frc_rings<<<grid, 256, 0, stream>>>(f1r, f1i, f2r, f2i, out);
}

// Round 6
// 248.636 us; speedup vs baseline: 3.1588x; 3.1588x over previous
//
#include <hip/hip_runtime.h>
#include <stdint.h>

#define BATCH 64
#define HH 512
#define NR 256
#define BANDH 8
#define NBANDS (256 / BANDH)   // 32 bands over dy' in [0,256)

// LDS aperture: low 32 bits of a generic pointer to __shared__ = LDS offset.
__device__ __forceinline__ uint32_t lds_off(const void* p) {
    return (uint32_t)(uintptr_t)p;
}

// Native fire-and-forget LDS fp32 atomics into 4 comp-major tables of 257
// floats (strides 1028 B). Comp-major => flushing lanes hold mostly-distinct
// consecutive bins at 4-B stride -> perfect bank spread. NO "memory" clobber:
// the compiler may (and should) hoist the next step's global loads above
// these; ordering vs the merge phase is enforced by the explicit waitcnt asm
// (which does clobber memory) + __syncthreads.
__device__ __forceinline__ void lds_add4(uint32_t addr, float v0, float v1,
                                         float v2, float v3) {
    asm volatile(
        "ds_add_f32 %0, %1\n\t"
        "ds_add_f32 %0, %2 offset:1028\n\t"
        "ds_add_f32 %0, %3 offset:2056\n\t"
        "ds_add_f32 %0, %4 offset:3084"
        :: "v"(addr), "v"(v0), "v"(v1), "v"(v2), "v"(v3));
}

__device__ __forceinline__ void gl_add(float* p, float v) {
    asm volatile("global_atomic_add_f32 %0, %1, off"
                 :: "v"(p), "v"(v) : "memory");
}

// 4-fold mirror + column-run-length scatter.
// Lane owns column dx = 64*wave + lane (0..255); block covers one batch and a
// band of dy' = 0..BANDH-1 rows; the 4 mirror pixels (+-dx, +-dy) share one
// bin, so their products fold into ONE register accumulator, flushed to LDS
// only when the bin changes along dy (<=1 step/row). Loads are coalesced
// (4 B/lane, contiguous 256-B spans). x=0 / y=0 lines have bin>=256 (dropped
// by reference) and are never touched.
__global__ __launch_bounds__(256) void frc_fold(
    const float* __restrict__ f1r, const float* __restrict__ f1i,
    const float* __restrict__ f2r, const float* __restrict__ f2i,
    float* __restrict__ gacc /* [BATCH][4][NR] */)
{
    __shared__ float s_acc[4 * 257];   // [comp][bin], bin 256 = overflow
    for (int i = threadIdx.x; i < 4 * 257; i += 256) s_acc[i] = 0.f;
    __syncthreads();

    const int b    = blockIdx.y;
    const int band = blockIdx.x;
    const int w    = threadIdx.x >> 6;
    const int lane = threadIdx.x & 63;
    const int dx   = w * 64 + lane;          // 0..255
    const int dx2  = dx * dx;
    const int wmin2 = (w * 64) * (w * 64);   // min dx^2 in this wave
    const float mx = (dx == 0) ? 0.f : 1.f;  // dx=0 is its own x-mirror

    const int dy0 = band * BANDH;
    const size_t ib = (size_t)b * HH * HH;
    const uint32_t sbase = lds_off(s_acc);

    float acr = 0.f, aci = 0.f, ap1 = 0.f, ap2 = 0.f;
    int cur = -1;

    for (int dy = dy0; dy < dy0 + BANDH; ++dy) {
        if (wmin2 + dy * dy >= 65536) break;  // whole wave in overflow bins

        const int r2 = dx2 + dy * dy;         // < 2^18, exact in fp32
        int bin = (int)sqrtf((float)r2);
        bin -= (bin * bin > r2);
        bin += ((bin + 1) * (bin + 1) <= r2);
        if (bin > 256) bin = 256;

        const float my = (dy == 0) ? 0.f : 1.f;  // dy=0 is its own y-mirror

        const size_t rp = ib + (size_t)(256 + dy) * HH;
        const size_t rm = ib + (size_t)(256 - dy) * HH;
        const int xp = 256 + dx;   // 256..511
        const int xm = 256 - dx;   // 1..256

        const float A1 = f1r[rp + xp], B1 = f1i[rp + xp];
        const float A2 = f2r[rp + xp], B2 = f2i[rp + xp];
        const float C1 = f1r[rp + xm], D1 = f1i[rp + xm];
        const float C2 = f2r[rp + xm], D2 = f2i[rp + xm];
        const float E1 = f1r[rm + xp], G1 = f1i[rm + xp];
        const float E2 = f2r[rm + xp], G2 = f2i[rm + xp];
        const float P1 = f1r[rm + xm], Q1 = f1i[rm + xm];
        const float P2 = f2r[rm + xm], Q2 = f2i[rm + xm];

        // folded products over up to 4 mirror pixels
        float scr = A1 * A2 + B1 * B2;
        float sci = B1 * A2 - A1 * B2;
        float sp1 = A1 * A1 + B1 * B1;
        float sp2 = A2 * A2 + B2 * B2;

        scr += mx * (C1 * C2 + D1 * D2);
        sci += mx * (D1 * C2 - C1 * D2);
        sp1 += mx * (C1 * C1 + D1 * D1);
        sp2 += mx * (C2 * C2 + D2 * D2);

        scr += my * (E1 * E2 + G1 * G2);
        sci += my * (G1 * E2 - E1 * G2);
        sp1 += my * (E1 * E1 + G1 * G1);
        sp2 += my * (E2 * E2 + G2 * G2);

        const float mxy = mx * my;
        scr += mxy * (P1 * P2 + Q1 * Q2);
        sci += mxy * (Q1 * P2 - P1 * Q2);
        sp1 += mxy * (P1 * P1 + Q1 * Q1);
        sp2 += mxy * (P2 * P2 + Q2 * Q2);

        if (bin != cur) {
            if (cur >= 0)
                lds_add4(sbase + 4u * (uint32_t)cur, acr, aci, ap1, ap2);
            acr = 0.f; aci = 0.f; ap1 = 0.f; ap2 = 0.f;
            cur = bin;
        }
        acr += scr; aci += sci; ap1 += sp1; ap2 += sp2;
    }
    if (cur >= 0)
        lds_add4(sbase + 4u * (uint32_t)cur, acr, aci, ap1, ap2);

    // Drain the asm DS ops the compiler can't see, then merge.
    asm volatile("s_waitcnt lgkmcnt(0)" ::: "memory");
    __syncthreads();

    {
        const int r = threadIdx.x;  // 256 threads -> bins 0..255 (drop 256)
        const float v0 = s_acc[0 * 257 + r];
        const float v1 = s_acc[1 * 257 + r];
        const float v2 = s_acc[2 * 257 + r];
        const float v3 = s_acc[3 * 257 + r];
        if (v0 != 0.f || v1 != 0.f || v2 != 0.f || v3 != 0.f) {
            float* g = gacc + (size_t)b * 4 * NR + r;
            gl_add(g + 0 * NR, v0);
            gl_add(g + 1 * NR, v1);
            gl_add(g + 2 * NR, v2);
            gl_add(g + 3 * NR, v3);
        }
    }
}

__global__ __launch_bounds__(NR) void frc_finalize(
    const float* __restrict__ gacc, float* __restrict__ out)
{
    const int b = blockIdx.x;
    const int r = threadIdx.x;
    const float* g = gacc + (size_t)b * 4 * NR + r;
    const float cr = g[0 * NR], ci = g[1 * NR], p1 = g[2 * NR], p2 = g[3 * NR];
    const float num = sqrtf(cr * cr + ci * ci);
    const float den = sqrtf(p1 * p2);
    out[(size_t)b * NR + r] = (den == 0.f) ? 0.f : num / den;
}

extern "C" void kernel_launch(void* const* d_in, const int* in_sizes, int n_in,
                              void* d_out, int out_size, void* d_ws, size_t ws_size,
                              hipStream_t stream) {
    const float* f1r = (const float*)d_in[0];
    const float* f1i = (const float*)d_in[1];
    const float* f2r = (const float*)d_in[2];
    const float* f2i = (const float*)d_in[3];
    float* out  = (float*)d_out;
    float* gacc = (float*)d_ws;   // BATCH*4*NR floats = 256 KiB

    (void)in_sizes; (void)n_in; (void)out_size; (void)ws_size;

    hipMemsetAsync(gacc, 0, (size_t)BATCH * 4 * NR * sizeof(float), stream);

    dim3 grid(NBANDS, BATCH);   // 32 x 64 = 2048 blocks, 8/CU
    frc_fold<<<grid, 256, 0, stream>>>(f1r, f1i, f2r, f2i, gacc);
    frc_finalize<<<dim3(BATCH), dim3(NR), 0, stream>>>(gacc, out);
}